// Round 1
// baseline (5067.897 us; speedup 1.0000x reference)
//
#include <hip/hip_runtime.h>
#include <math.h>

// ---------------------------------------------------------------------------
// ProbMambaHead: time-varying SSM + per-step Kalman filter.
// Phase 1 (proj_kernel): per-(b,t) projections -> 256-float record in d_ws.
// Phase 2 (scan_kernel): 1 wave per batch chain, wave-synchronous (no
//   __syncthreads -> prefetch loads never drained by barrier vmcnt(0)).
// Phase 3 (finalize_kernel): nll / avg_ll scalars.
// ---------------------------------------------------------------------------

#define FENCE() asm volatile("" ::: "memory")   // compiler-only memory fence;
// same-wave LDS ops are processed in order by HW, so this is sufficient for
// wave-synchronous cross-lane LDS communication (no barrier instruction).

constexpr int NB   = 32;
constexpr int TSEQ = 2048;
constexpr int BT   = NB * TSEQ;   // 65536
constexpr int DF   = 128;
constexpr int NS   = 16;          // state dim n
constexpr int DYV  = 8;           // obs dim dy
constexpr int REC  = 256;         // floats per (b,t) record (pad to 64 float4)
constexpr int TB   = 16;          // timesteps per proj block

#define LOG2PI_F 1.8378770664093453f

__device__ __forceinline__ float sp_(float v) {          // jax.nn.softplus
    return v > 0.f ? v + log1pf(expf(-v)) : log1pf(expf(v));
}
__device__ __forceinline__ float dot4_(float4 a, float4 b) {
    return a.x*b.x + a.y*b.y + a.z*b.z + a.w*b.w;
}

// ---------------------------------------------------------------------------
// Phase 1: projections.
// Record layout: [0:16) exp_z | [16:32) hx | [32:48) q | [48:176) C (d*16+j)
//                | [176:184) R | [184:192) y | pad to 256.
// ---------------------------------------------------------------------------
__global__ __launch_bounds__(256) void proj_kernel(
    const float* __restrict__ x, const float* __restrict__ y,
    const float* __restrict__ a_raw,
    const float* __restrict__ Wg,  const float* __restrict__ bg,
    const float* __restrict__ WBm, const float* __restrict__ bB,
    const float* __restrict__ WC,  const float* __restrict__ bC,
    const float* __restrict__ Wsg, const float* __restrict__ bsg,
    const float* __restrict__ WR,  const float* __restrict__ bR,
    float* __restrict__ rec)
{
    __shared__ __align__(16) float XsT[DF * TB];   // [f][t] transposed x tile
    __shared__ __align__(16) float Dsh[TB];        // Delta per t
    __shared__ __align__(16) float sigS[TB * NS];  // [t][i]
    __shared__ __align__(16) float bbS[TB * NS];   // [t][i]  b_B . x per block i
    __shared__ __align__(16) float hxS[TB * NS];   // [t][i]  x^T M_i x

    const int tid = threadIdx.x;
    const long bt0 = (long)blockIdx.x * TB;

    // load + transpose x tile (scalar writes: one-time 32-way conflict, cheap)
    for (int idx = tid; idx < TB * DF; idx += 256) {
        int t = idx >> 7, f = idx & 127;
        XsT[f * TB + t] = x[(bt0 + t) * DF + f];
    }
    __syncthreads();

    // ---- stage B: small heads (gate 1 + sig 16 + R 8 + C 128 + b_B 16 rows)
    for (int jb = tid; jb < 169 * TB; jb += 256) {
        int r = jb >> 4, t = jb & 15;
        const float* wrow; float bias; int kind, sub;
        if (r == 0)       { wrow = Wg;                 bias = bg[0];     kind = 0; sub = 0; }
        else if (r < 17)  { sub = r - 1;   wrow = Wsg + sub * DF; bias = bsg[sub]; kind = 1; }
        else if (r < 25)  { sub = r - 17;  wrow = WR  + sub * DF; bias = bR[sub];  kind = 2; }
        else if (r < 153) { sub = r - 25;  wrow = WC  + sub * DF; bias = bC[sub];  kind = 3; }
        else              { sub = r - 153; wrow = bB  + sub * DF; bias = 0.f;      kind = 4; }
        const float4* w4 = (const float4*)wrow;
        float dot = bias;
        #pragma unroll 8
        for (int g4 = 0; g4 < 32; ++g4) {
            float4 w = w4[g4];
            const float* xp = XsT + (g4 * 4) * TB + t;
            dot += w.x * xp[0] + w.y * xp[TB] + w.z * xp[2 * TB] + w.w * xp[3 * TB];
        }
        long bt = bt0 + t;
        if (kind == 0)      Dsh[t] = fminf(fmaxf(sp_(dot) + 1e-6f, 1e-3f), 1.0f);
        else if (kind == 1) sigS[t * NS + sub] = sp_(dot) + 1e-6f + 1e-3f;
        else if (kind == 2) rec[bt * REC + 176 + sub] = sp_(dot) + 1e-6f + 1e-4f;
        else if (kind == 3) rec[bt * REC + 48 + sub] = dot;
        else                bbS[t * NS + sub] = dot;
    }
    // copy y into records
    if (tid < TB * DYV) {
        int t = tid >> 3, d = tid & 7;
        rec[(bt0 + t) * REC + 184 + d] = y[(bt0 + t) * DYV + d];
    }

    // ---- stage C: hx quadratic form. 4 consecutive W_B rows per thread.
    for (int p = 0; p < 2; ++p) {
        int row0 = p * 1024 + tid * 4;   // rows row0..row0+3, all same i-block
        int iblk = row0 >> 7;
        int f0   = row0 & 127;
        float acc[4][16];
        #pragma unroll
        for (int r = 0; r < 4; ++r)
            #pragma unroll
            for (int t = 0; t < 16; ++t) acc[r][t] = 0.f;
        const float4* w40 = (const float4*)(WBm + (size_t)(row0 + 0) * DF);
        const float4* w41 = (const float4*)(WBm + (size_t)(row0 + 1) * DF);
        const float4* w42 = (const float4*)(WBm + (size_t)(row0 + 2) * DF);
        const float4* w43 = (const float4*)(WBm + (size_t)(row0 + 3) * DF);
        for (int g4 = 0; g4 < 32; ++g4) {
            float4 w0 = w40[g4], w1 = w41[g4], w2 = w42[g4], w3 = w43[g4];
            float wa[4][4] = {{w0.x,w0.y,w0.z,w0.w},{w1.x,w1.y,w1.z,w1.w},
                              {w2.x,w2.y,w2.z,w2.w},{w3.x,w3.y,w3.z,w3.w}};
            #pragma unroll
            for (int gg = 0; gg < 4; ++gg) {
                const float4* xr = (const float4*)(XsT + (g4 * 4 + gg) * TB);
                float4 xa = xr[0], xb = xr[1], xc = xr[2], xd = xr[3];
                float xv[16] = {xa.x,xa.y,xa.z,xa.w, xb.x,xb.y,xb.z,xb.w,
                                xc.x,xc.y,xc.z,xc.w, xd.x,xd.y,xd.z,xd.w};
                #pragma unroll
                for (int t = 0; t < 16; ++t) {
                    acc[0][t] += wa[0][gg] * xv[t];
                    acc[1][t] += wa[1][gg] * xv[t];
                    acc[2][t] += wa[2][gg] * xv[t];
                    acc[3][t] += wa[3][gg] * xv[t];
                }
            }
        }
        // multiply by x[t][f_r] and reduce the 4 local rows
        float part[16];
        #pragma unroll
        for (int t = 0; t < 16; ++t) part[t] = 0.f;
        #pragma unroll
        for (int r = 0; r < 4; ++r) {
            const float4* xr = (const float4*)(XsT + (f0 + r) * TB);
            float4 xa = xr[0], xb = xr[1], xc = xr[2], xd = xr[3];
            float xv[16] = {xa.x,xa.y,xa.z,xa.w, xb.x,xb.y,xb.z,xb.w,
                            xc.x,xc.y,xc.z,xc.w, xd.x,xd.y,xd.z,xd.w};
            #pragma unroll
            for (int t = 0; t < 16; ++t) part[t] += acc[r][t] * xv[t];
        }
        // reduce across the 32 consecutive lanes sharing iblk
        #pragma unroll
        for (int off = 1; off <= 16; off <<= 1) {
            #pragma unroll
            for (int t = 0; t < 16; ++t) part[t] += __shfl_xor(part[t], off, 64);
        }
        if ((tid & 31) == 0) {
            #pragma unroll
            for (int t = 0; t < 16; ++t) hxS[t * NS + iblk] = part[t];
        }
    }
    __syncthreads();

    // ---- combine: one thread per (t,i)
    {
        int t = tid >> 4, i = tid & 15;
        float D  = Dsh[t];
        float a  = -(sp_(a_raw[i]) + 1e-6f);
        float z  = fminf(fmaxf(D * a, -20.f), 20.f);
        float ez = expf(z);
        float gam = (fabsf(z) < 1e-4f) ? (1.f + 0.5f * z) : (expm1f(z) / z);
        float z2  = 2.f * z;
        float rho = (fabsf(z2) < 1e-4f) ? (1.f + 0.5f * z2) : (expm1f(z2) / z2);
        float hxv = gam * D * (hxS[t * NS + i] + bbS[t * NS + i]);
        float sg  = sigS[t * NS + i];
        float qv  = sg * sg * rho * D;
        long base = (bt0 + t) * REC;
        rec[base + i]      = ez;
        rec[base + 16 + i] = hxv;
        rec[base + 32 + i] = qv;
    }
}

// ---------------------------------------------------------------------------
// Phase 2: sequential Kalman scan. One wave (64 lanes) per batch element.
// Wave-synchronous: no __syncthreads, so the t+1 prefetch load stays in
// flight across stage boundaries (FENCE is compile-time only).
// ---------------------------------------------------------------------------
__global__ __launch_bounds__(64) void scan_kernel(
    const float* __restrict__ rec, const float* __restrict__ p0,
    float* __restrict__ out_ym, float* __restrict__ out_var,
    float* __restrict__ llsum)
{
    const int b = blockIdx.x;
    const int l = threadIdx.x;

    __shared__ __align__(16) float Ps[REC];        // current record
    __shared__ __align__(16) float hS[NS];
    __shared__ __align__(16) float hpred[NS];
    __shared__ __align__(16) float P[NS * NS];     // symmetric
    __shared__ __align__(16) float Ppred[NS * NS]; // symmetric
    __shared__ __align__(16) float CPm[DYV * NS];  // [d][m]
    __shared__ __align__(16) float CPT[NS * DYV];  // [m][d]
    __shared__ __align__(16) float Sinv[DYV * DYV];
    __shared__ __align__(16) float Km[NS * DYV];   // [i][d]
    __shared__ __align__(16) float er[DYV];
    __shared__ __align__(16) float v8[DYV];

    // init state: h = 0, P = diag(|p0|)
    {
        int i = l >> 2, jb = (l & 3) * 4;
        float pv = fabsf(p0[i]);
        float tmp[4];
        #pragma unroll
        for (int k = 0; k < 4; ++k) tmp[k] = (jb + k == i) ? pv : 0.f;
        ((float4*)P)[l] = make_float4(tmp[0], tmp[1], tmp[2], tmp[3]);
        if (l < NS) hS[l] = 0.f;
    }
    FENCE();

    const float4* rec4 = (const float4*)rec;
    float4 pf = rec4[((long)b * TSEQ) * 64 + l];
    float accll = 0.f;

    for (int t = 0; t < TSEQ; ++t) {
        ((float4*)Ps)[l] = pf;                       // stage 0: params -> LDS
        FENCE();
        if (t + 1 < TSEQ) pf = rec4[((long)b * TSEQ + t + 1) * 64 + l]; // prefetch

        // stage 1: P_pred, h_pred
        {
            int i = l >> 2, jb = (l & 3) * 4;
            float ei = Ps[i];
            float4 ej = ((const float4*)Ps)[l & 3];
            float4 Pv = ((const float4*)P)[l];
            float tmp[4] = { ei*ej.x*Pv.x, ei*ej.y*Pv.y, ei*ej.z*Pv.z, ei*ej.w*Pv.w };
            if ((l & 3) == (i >> 2)) tmp[i & 3] += Ps[32 + i];   // + q on diag
            ((float4*)Ppred)[l] = make_float4(tmp[0], tmp[1], tmp[2], tmp[3]);
            if (l < NS) hpred[l] = Ps[l] * hS[l] + Ps[16 + l];
        }
        FENCE();

        // stage 2: CP = C P_pred (rows x rows: P_pred symmetric), y_pred, e
        {
            int d = l >> 3, mb = (l & 7) * 2;
            const float4* Cr = (const float4*)(Ps + 48 + d * 16);
            float4 c0 = Cr[0], c1 = Cr[1], c2 = Cr[2], c3 = Cr[3];
            const float4* P0 = (const float4*)(Ppred + mb * 16);
            const float4* P1 = (const float4*)(Ppred + (mb + 1) * 16);
            float cp0 = dot4_(c0,P0[0]) + dot4_(c1,P0[1]) + dot4_(c2,P0[2]) + dot4_(c3,P0[3]);
            float cp1 = dot4_(c0,P1[0]) + dot4_(c1,P1[1]) + dot4_(c2,P1[2]) + dot4_(c3,P1[3]);
            CPm[d * 16 + mb]     = cp0;  CPm[d * 16 + mb + 1] = cp1;
            CPT[mb * 8 + d]      = cp0;  CPT[(mb + 1) * 8 + d] = cp1;
            if (l < DYV) {
                const float4* Cy = (const float4*)(Ps + 48 + l * 16);
                const float4* hp = (const float4*)hpred;
                float yp = dot4_(Cy[0],hp[0]) + dot4_(Cy[1],hp[1])
                         + dot4_(Cy[2],hp[2]) + dot4_(Cy[3],hp[3]);
                er[l] = Ps[184 + l] - yp;
                out_ym[((long)b * TSEQ + t) * 8 + l] = yp;
            }
        }
        FENCE();

        // stage 3: S (registers, lane = d*8+e), Gauss-Jordan inverse + logdet
        float ldet;
        {
            int d = l >> 3, e = l & 7;
            const float4* CPr = (const float4*)(CPm + d * 16);
            const float4* Ce  = (const float4*)(Ps + 48 + e * 16);
            float s = dot4_(CPr[0],Ce[0]) + dot4_(CPr[1],Ce[1])
                    + dot4_(CPr[2],Ce[2]) + dot4_(CPr[3],Ce[3]);
            if (d == e) {
                s += Ps[176 + d];
                out_var[((long)b * TSEQ + t) * 8 + d] = s;   // Sdiag output
            }
            float A = s, In = (d == e) ? 1.f : 0.f;
            float pdet = 1.f;
            #pragma unroll
            for (int k = 0; k < 8; ++k) {
                float piv  = __shfl(A, k * 9, 64);
                float f    = __shfl(A, d * 8 + k, 64);
                float arow = __shfl(A, k * 8 + e, 64);
                float irow = __shfl(In, k * 8 + e, 64);
                float ipiv = 1.f / piv;
                pdet *= piv;
                float fr = f * ipiv;
                bool isk = (d == k);
                A  = isk ? A  * ipiv : A  - fr * arow;
                In = isk ? In * ipiv : In - fr * irow;
            }
            Sinv[l] = In;
            ldet = logf(pdet);     // SPD: pivots > 0, product = det(S)
        }
        FENCE();

        // stage 4: K = (Sinv CP)^T   (K[i][d] = Sinv row d . CPT row i)
        {
            int i = l >> 2, db = (l & 3) * 2;
            const float4* ct = (const float4*)(CPT + i * 8);
            float4 cp0 = ct[0], cp1 = ct[1];
            const float4* s0 = (const float4*)(Sinv + db * 8);
            const float4* s1 = (const float4*)(Sinv + (db + 1) * 8);
            float k0 = dot4_(cp0, s0[0]) + dot4_(cp1, s0[1]);
            float k1 = dot4_(cp0, s1[0]) + dot4_(cp1, s1[1]);
            Km[i * 8 + db]     = k0;
            Km[i * 8 + db + 1] = k1;
        }
        FENCE();

        // stage 5: h_new, v = Sinv e
        {
            if (l < NS) {
                const float4* kr = (const float4*)(Km + l * 8);
                const float4* e4 = (const float4*)er;
                hS[l] = hpred[l] + dot4_(kr[0], e4[0]) + dot4_(kr[1], e4[1]);
            } else if (l < NS + DYV) {
                int d = l - NS;
                const float4* sr = (const float4*)(Sinv + d * 8);
                const float4* e4 = (const float4*)er;
                v8[d] = dot4_(sr[0], e4[0]) + dot4_(sr[1], e4[1]);
            }
        }
        FENCE();

        // stage 6: P_new = P_pred - 0.5*(K CP + (K CP)^T)  (== Joseph exactly),
        //          log-likelihood accumulate
        {
            int i = l >> 2, jb = (l & 3) * 4;
            const float4* Ki = (const float4*)(Km + i * 8);
            float4 ki0 = Ki[0], ki1 = Ki[1];
            const float4* Ci = (const float4*)(CPT + i * 8);
            float4 ci0 = Ci[0], ci1 = Ci[1];
            float4 Pp = ((const float4*)Ppred)[l];
            float pp[4] = {Pp.x, Pp.y, Pp.z, Pp.w};
            float tmp[4];
            #pragma unroll
            for (int m = 0; m < 4; ++m) {
                int j = jb + m;
                const float4* Cj = (const float4*)(CPT + j * 8);
                const float4* Kj = (const float4*)(Km + j * 8);
                float da  = dot4_(ki0, Cj[0]) + dot4_(ki1, Cj[1]);
                float db_ = dot4_(Kj[0], ci0) + dot4_(Kj[1], ci1);
                tmp[m] = pp[m] - 0.5f * (da + db_);
            }
            ((float4*)P)[l] = make_float4(tmp[0], tmp[1], tmp[2], tmp[3]);
            if (l == 0) {
                float quad = 0.f;
                #pragma unroll
                for (int d2 = 0; d2 < 8; ++d2) quad += er[d2] * v8[d2];
                accll += -0.5f * (ldet + quad + 8.f * LOG2PI_F);
            }
        }
        FENCE();
    }
    if (l == 0) llsum[b] = accll;
}

// ---------------------------------------------------------------------------
// Phase 3: scalars
// ---------------------------------------------------------------------------
__global__ void finalize_kernel(const float* __restrict__ llsum,
                                float* __restrict__ out)
{
    if (threadIdx.x == 0 && blockIdx.x == 0) {
        float s = 0.f;
        for (int b2 = 0; b2 < NB; ++b2) s += llsum[b2];
        out[(size_t)2 * BT * DYV]     = -s / (float)NB;        // nll
        out[(size_t)2 * BT * DYV + 1] =  s / (float)BT;        // avg_ll_per_step
    }
}

extern "C" void kernel_launch(void* const* d_in, const int* in_sizes, int n_in,
                              void* d_out, int out_size, void* d_ws, size_t ws_size,
                              hipStream_t stream) {
    const float* x     = (const float*)d_in[0];
    const float* y     = (const float*)d_in[1];
    const float* a_raw = (const float*)d_in[2];
    const float* Wg    = (const float*)d_in[3];
    const float* bg    = (const float*)d_in[4];
    const float* WBm   = (const float*)d_in[5];
    const float* bB    = (const float*)d_in[6];
    const float* WC    = (const float*)d_in[7];
    const float* bC    = (const float*)d_in[8];
    const float* Wsg   = (const float*)d_in[9];
    const float* bsg   = (const float*)d_in[10];
    const float* WR    = (const float*)d_in[11];
    const float* bR    = (const float*)d_in[12];
    const float* p0    = (const float*)d_in[13];

    float* rec   = (float*)d_ws;                       // 65536 * 256 floats = 64 MB
    float* llsum = rec + (size_t)BT * REC;             // + 32 floats
    float* out   = (float*)d_out;

    proj_kernel<<<BT / TB, 256, 0, stream>>>(x, y, a_raw, Wg, bg, WBm, bB,
                                             WC, bC, Wsg, bsg, WR, bR, rec);
    scan_kernel<<<NB, 64, 0, stream>>>(rec, p0, out, out + (size_t)BT * DYV, llsum);
    finalize_kernel<<<1, 64, 0, stream>>>(llsum, out);
}